// Round 8
// baseline (239.516 us; speedup 1.0000x reference)
//
#include <hip/hip_runtime.h>

// Embedding-bag: out[b,:] = bias + sum_k vals[b,k] * weight[ics[b,k],:]
// B=16384, K=32, N_OUT=256.
//
// - 8 column-slices of 32 cols; slice = blockIdx % 8 -> XCD round-robin;
//   per-XCD gather slab 5.25 MiB -> ~81% L2 hit (measured R2: FETCH 97 MB
//   vs 512 MB demand). Grid stays 4096 blocks (R5 showed shrinking it to
//   1024 collapses occupancy to 16%).
// - MLP via 8 INDEPENDENT K-chains per lane (chain c = k 4c..4c+3, own
//   accumulator): ordering by register data dependence only — no manual
//   waitcnt (R7: compiler hoisted ds_reads over it -> race, absmax 7e-3),
//   no sched fences (R4: spills), no row-chains (R5: grid shrank).
//   R5's VGPR=88 proved independent chains force the compiler to keep
//   N gathers in flight.
// - (idx,val) staged once in LDS transposed [k*8+r]: conflict-free, 8-lane
//   broadcast per read, no persistent idx VGPRs.
// - __launch_bounds__(256,4): pressure target 128 VGPR so the scheduler
//   doesn't re-serialize to the 64-VGPR MLP=1 schedule (R2/R3 failure mode).

constexpr int K = 32;

__global__ __launch_bounds__(256, 4) void FeatureTransformer_45896020525219_kernel(
    const int* __restrict__ ics,
    const float* __restrict__ vals,
    const float4* __restrict__ w4,     // [N_IN * 64]
    const float4* __restrict__ bias4,  // [64]
    float4* __restrict__ out4,         // [B * 64]
    int B)
{
    __shared__ int2 parm[4][K * 8];    // per wave: [(k*8)+r], 2 KiB

    const int lane   = threadIdx.x & 63;
    const int wave   = threadIdx.x >> 6;
    const int slice  = blockIdx.x & 7;   // -> XCD (L2 locality)
    const int rowblk = blockIdx.x >> 3;

    const int r  = lane >> 3;            // row-group 0..7 in wave
    const int c4 = lane & 7;             // float4-column in the 32-col slice
    const int b  = rowblk * 32 + wave * 8 + r;
    if (b >= B) return;

    const int colbase = slice * 8 + c4;  // float4 index within the 64 per row

    // ---- stage (idx,val) params to LDS, transposed [k*8 + r] ----
    const int4   iq = ((const int4*)  (ics  + (size_t)b * K))[c4];
    const float4 fq = ((const float4*)(vals + (size_t)b * K))[c4];
    {
        int2* p = parm[wave];
        p[(c4 * 4 + 0) * 8 + r] = make_int2(iq.x, __float_as_int(fq.x));
        p[(c4 * 4 + 1) * 8 + r] = make_int2(iq.y, __float_as_int(fq.y));
        p[(c4 * 4 + 2) * 8 + r] = make_int2(iq.z, __float_as_int(fq.z));
        p[(c4 * 4 + 3) * 8 + r] = make_int2(iq.w, __float_as_int(fq.w));
    }
    __syncthreads();

    const float4* wb = w4 + colbase;

    float4 acc[8];
    #pragma unroll
    for (int c = 0; c < 8; ++c) acc[c] = make_float4(0.f, 0.f, 0.f, 0.f);

    #pragma unroll
    for (int u = 0; u < 4; ++u) {        // step within each chain
        float  v[8];
        float4 w[8];
        #pragma unroll
        for (int c = 0; c < 8; ++c) {    // 8 independent gathers in flight
            const int2 P = parm[wave][(c * 4 + u) * 8 + r];   // LDS broadcast
            const int  j = P.x;
            v[c] = (j >= 0) ? __int_as_float(P.y) : 0.0f;     // branchless pad
            const unsigned uj = (j >= 0) ? (unsigned)j : 0u;
            w[c] = wb[(size_t)uj * 64];
        }
        #pragma unroll
        for (int c = 0; c < 8; ++c) {
            acc[c].x = fmaf(v[c], w[c].x, acc[c].x);
            acc[c].y = fmaf(v[c], w[c].y, acc[c].y);
            acc[c].z = fmaf(v[c], w[c].z, acc[c].z);
            acc[c].w = fmaf(v[c], w[c].w, acc[c].w);
        }
    }

    // combine chains + bias (fp32 reassociation ~1e-6 << 1e-3 threshold)
    float4 o = bias4[colbase];
    #pragma unroll
    for (int c = 0; c < 8; ++c) {
        o.x += acc[c].x;  o.y += acc[c].y;
        o.z += acc[c].z;  o.w += acc[c].w;
    }
    out4[(size_t)b * 64 + colbase] = o;
}

extern "C" void kernel_launch(void* const* d_in, const int* in_sizes, int n_in,
                              void* d_out, int out_size, void* d_ws, size_t ws_size,
                              hipStream_t stream) {
    const int*    ics   = (const int*)d_in[0];
    const float*  vals  = (const float*)d_in[1];
    const float4* w4    = (const float4*)d_in[2];
    const float4* bias4 = (const float4*)d_in[3];
    float4*       out4  = (float4*)d_out;

    const int B = in_sizes[0] / K;            // 16384
    const int blocks = ((B + 31) / 32) * 8;   // 32 rows/block x 8 slices = 4096

    hipLaunchKernelGGL(FeatureTransformer_45896020525219_kernel,
                       dim3(blocks), dim3(256), 0, stream,
                       ics, vals, w4, bias4, out4, B);
}